// Round 1
// baseline (1541.652 us; speedup 1.0000x reference)
//
#include <hip/hip_runtime.h>
#include <hip/hip_bf16.h>
#include <math.h>

#define N_NODES 50000
#define N_EDGES 800000
#define D_NODE 64
#define D_EDGE 32
#define OUT_DIM 32
#define NUM_HEADS 4
#define HD 128            // NUM_HEADS*OUT_DIM
#define NCH 49            // ceil(N_NODES/1024)

// ---- monotone float<->uint encoding for atomicMax on floats ----
__device__ __forceinline__ unsigned encf(float x) {
    unsigned b = __float_as_uint(x);
    return (b & 0x80000000u) ? ~b : (b | 0x80000000u);
}
__device__ __forceinline__ float decf(unsigned u) {
    unsigned b = (u & 0x80000000u) ? (u & 0x7FFFFFFFu) : ~u;
    return __uint_as_float(b);
}
#define ENC_NEGINF 0x007FFFFFu   // encf(-inf)

// ---- K0: detect attn_mask storage dtype (u8 / f32 / i32) ----
// bernoulli(0.95): nonzero-byte fraction ~0.95 (u8), ~0.475 (f32 1.0f), ~0.2375 (i32)
__global__ void k_detect(const unsigned char* __restrict__ mask, int* __restrict__ mode) {
    __shared__ int cnt;
    if (threadIdx.x == 0) cnt = 0;
    __syncthreads();
    int c = 0;
    for (int i = threadIdx.x; i < 4096; i += 256) c += (mask[i] != 0);
    atomicAdd(&cnt, c);
    __syncthreads();
    if (threadIdx.x == 0) {
        int md;
        if (cnt > (4096 * 70) / 100)      md = 0;  // uint8 bool
        else if (cnt > (4096 * 35) / 100) md = 1;  // float32
        else                              md = 2;  // int32
        *mode = md;
    }
}

// ---- K1: node precompute GEMM: P = nf @ Wblk, three [64x128] weight blocks ----
// grid (ceil(N/64), 3), block 256
__global__ __launch_bounds__(256) void k_nodegemm(
    const float* __restrict__ nf, const float* __restrict__ Wa, const float* __restrict__ Wm,
    float* __restrict__ Psrc, float* __restrict__ Ptgta, float* __restrict__ Ptgtm) {
    __shared__ float At[64][72];    // [k][row], padded
    __shared__ float Bt[64][128];   // [k][col]
    const int mb = blockIdx.y;
    const float* Wsrc = (mb == 0) ? Wa : (mb == 1 ? (Wa + 96 * 128) : (Wm + 32 * 128));
    float* P = (mb == 0) ? Psrc : (mb == 1 ? Ptgta : Ptgtm);
    const int n0 = blockIdx.x * 64;
    const int tid = threadIdx.x;

    for (int i = tid; i < 1024; i += 256) {       // A tile: 64 rows x 64 k, transposed into LDS
        int r = i >> 4;
        int kc = (i & 15) << 2;
        float4 v = make_float4(0.f, 0.f, 0.f, 0.f);
        if (n0 + r < N_NODES) v = *(const float4*)(nf + (size_t)(n0 + r) * 64 + kc);
        At[kc + 0][r] = v.x; At[kc + 1][r] = v.y; At[kc + 2][r] = v.z; At[kc + 3][r] = v.w;
    }
    for (int i = tid; i < 2048; i += 256) {       // B tile: 64 k x 128 cols
        int k = i >> 5;
        int c = (i & 31) << 2;
        *(float4*)(&Bt[k][c]) = *(const float4*)(Wsrc + (size_t)k * 128 + c);
    }
    __syncthreads();

    const int ty = tid >> 5;   // 0..7 -> 8 rows each
    const int tx = tid & 31;   // 0..31 -> 4 cols each
    float acc[8][4];
#pragma unroll
    for (int r = 0; r < 8; r++)
#pragma unroll
        for (int c = 0; c < 4; c++) acc[r][c] = 0.f;

    for (int k = 0; k < 64; k++) {
        float4 b = *(const float4*)(&Bt[k][tx * 4]);
        float4 a0 = *(const float4*)(&At[k][ty * 8]);
        float4 a1 = *(const float4*)(&At[k][ty * 8 + 4]);
        float a[8] = {a0.x, a0.y, a0.z, a0.w, a1.x, a1.y, a1.z, a1.w};
#pragma unroll
        for (int r = 0; r < 8; r++) {
            acc[r][0] += a[r] * b.x; acc[r][1] += a[r] * b.y;
            acc[r][2] += a[r] * b.z; acc[r][3] += a[r] * b.w;
        }
    }
    for (int r = 0; r < 8; r++) {
        int n = n0 + ty * 8 + r;
        if (n < N_NODES)
            *(float4*)(P + (size_t)n * 128 + tx * 4) =
                make_float4(acc[r][0], acc[r][1], acc[r][2], acc[r][3]);
    }
}

// ---- K2: degree count ----
__global__ void k_deg(const int* __restrict__ src, int* __restrict__ deg) {
    int i = blockIdx.x * blockDim.x + threadIdx.x;
    if (i < N_EDGES) atomicAdd(&deg[src[i]], 1);
}

// ---- K3a: per-1024-chunk sums ----
__global__ void k_scan_partial(const int* __restrict__ deg, int* __restrict__ csum) {
    __shared__ int sd[256];
    int b = blockIdx.x, tid = threadIdx.x;
    int s = 0, st = b * 1024;
    for (int i = tid; i < 1024; i += 256) {
        int idx = st + i;
        if (idx < N_NODES) s += deg[idx];
    }
    sd[tid] = s; __syncthreads();
    for (int off = 128; off > 0; off >>= 1) {
        if (tid < off) sd[tid] += sd[tid + off];
        __syncthreads();
    }
    if (tid == 0) csum[b] = sd[0];
}

// ---- K3b: exclusive scan of chunk sums (tiny) ----
__global__ void k_scan_chunks(int* __restrict__ csum) {
    if (threadIdx.x == 0 && blockIdx.x == 0) {
        int acc = 0;
        for (int i = 0; i < NCH; i++) { int v = csum[i]; csum[i] = acc; acc += v; }
    }
}

// ---- K3c: in-chunk scan -> base offsets ----
__global__ __launch_bounds__(1024) void k_scan_apply(
    const int* __restrict__ deg, const int* __restrict__ csum, int* __restrict__ basep) {
    __shared__ int sd[1024];
    int b = blockIdx.x, tid = threadIdx.x;
    int idx = b * 1024 + tid;
    int v = (idx < N_NODES) ? deg[idx] : 0;
    sd[tid] = v; __syncthreads();
    for (int off = 1; off < 1024; off <<= 1) {
        int add = (tid >= off) ? sd[tid - off] : 0;
        __syncthreads();
        sd[tid] += add;
        __syncthreads();
    }
    if (idx < N_NODES) basep[idx] = csum[b] + sd[tid] - v;  // exclusive
}

// ---- K4: scatter edge ids into per-node buckets ----
__global__ void k_scatter(const int* __restrict__ src, const int* __restrict__ basep,
                          int* __restrict__ cursor, int* __restrict__ order) {
    int i = blockIdx.x * blockDim.x + threadIdx.x;
    if (i < N_EDGES) {
        int s = src[i];
        int p = basep[s] + atomicAdd(&cursor[s], 1);
        order[p] = i;
    }
}

// ---- K5: per-edge logits + per-(node,head) max via atomicMax ----
// block 128 threads (one edge at a time, 8 edges per block), grid = E/8
__global__ __launch_bounds__(128) void k_edge(
    const float* __restrict__ ef, const int* __restrict__ src, const int* __restrict__ tgt,
    const void* __restrict__ mask, const int* __restrict__ modep,
    const float* __restrict__ Wa, const float* __restrict__ aw,
    const float* __restrict__ Psrc, const float* __restrict__ Ptgta,
    float* __restrict__ logits, unsigned* __restrict__ nmax) {
    __shared__ float W[32][128];
    __shared__ float efb[2][32];
    const int tid = threadIdx.x;
    for (int i = tid; i < 1024; i += 128) {   // stage W_a rows 64..95
        int k = i >> 5;
        int c = (i & 31) << 2;
        *(float4*)(&W[k][c]) = *(const float4*)(Wa + (size_t)(64 + k) * 128 + c);
    }
    const int mode = *modep;
    const float awv = aw[tid & 31];
    const int e0 = blockIdx.x * 8;
    {
        int e = min(e0, N_EDGES - 1);
        if (tid < 32) efb[0][tid] = ef[(size_t)e * 32 + tid];
    }
    __syncthreads();

    for (int i = 0; i < 8; i++) {
        int e = e0 + i;
        if (i < 7 && tid < 32) {
            int en = min(e0 + i + 1, N_EDGES - 1);
            efb[(i + 1) & 1][tid] = ef[(size_t)en * 32 + tid];
        }
        if (e < N_EDGES) {
            int s = src[e], t = tgt[e];
            const float* eb = efb[i & 1];
            float x = 0.f;
#pragma unroll
            for (int k = 0; k < 32; k++) x += eb[k] * W[k][tid];
            float ha = x + Psrc[(size_t)s * 128 + tid] + Ptgta[(size_t)t * 128 + tid];
            float lr = (ha >= 0.f) ? ha : 0.2f * ha;
            float v = lr * awv;
            v += __shfl_xor(v, 16);
            v += __shfl_xor(v, 8);
            v += __shfl_xor(v, 4);
            v += __shfl_xor(v, 2);
            v += __shfl_xor(v, 1);
            bool mk;
            if (mode == 0)      mk = ((const unsigned char*)mask)[e] != 0;
            else if (mode == 1) mk = ((const float*)mask)[e] != 0.f;
            else                mk = ((const int*)mask)[e] != 0;
            float lg = mk ? v : -INFINITY;
            if ((tid & 31) == 0) {
                int h = tid >> 5;
                logits[(size_t)e * 4 + h] = lg;
                atomicMax(nmax + (size_t)s * 4 + h, encf(lg));
            }
        }
        __syncthreads();
    }
}

// ---- K6: node-centric softmax + message aggregation (wave per node) ----
// block 256 = 4 waves, grid ceil(N/4)
__global__ __launch_bounds__(256) void k_node(
    const float* __restrict__ ef, const int* __restrict__ tgt,
    const float* __restrict__ Wm, const float* __restrict__ Ptgtm,
    const float* __restrict__ logits, const unsigned* __restrict__ nmax,
    const int* __restrict__ deg, const int* __restrict__ basep,
    const int* __restrict__ order, float* __restrict__ out) {
    __shared__ float W[32][128];
    const int tid = threadIdx.x;
    for (int i = tid; i < 1024; i += 256) {   // stage W_m rows 0..31 (edge block)
        int k = i >> 5;
        int c = (i & 31) << 2;
        *(float4*)(&W[k][c]) = *(const float4*)(Wm + (size_t)k * 128 + c);
    }
    __syncthreads();

    const int wv = tid >> 6;
    const int lane = tid & 63;
    const int n = blockIdx.x * 4 + wv;
    if (n >= N_NODES) return;

    const int dg = deg[n], bs = basep[n];
    const bool dead = (nmax[(size_t)n * 4] <= ENC_NEGINF);
    float mx[4];
#pragma unroll
    for (int h = 0; h < 4; h++) mx[h] = decf(nmax[(size_t)n * 4 + h]);

    const int d0 = lane, d1 = lane + 64;
    const int h0 = d0 >> 5, h1 = d1 >> 5;
    float acc0 = 0.f, acc1 = 0.f;
    float den0 = 0.f, den1 = 0.f;   // denominators for h0 and h1 (same for all lanes in 32-group)

    for (int i = 0; i < dg; i++) {
        int e = order[bs + i];
        float efv = (lane < 32) ? ef[(size_t)e * 32 + lane] : 0.f;
        float4 lg = *(const float4*)(logits + (size_t)e * 4);
        float u[4];
        if (dead) {
            u[0] = u[1] = u[2] = u[3] = 1.f;
        } else {
            u[0] = __expf(lg.x - mx[0]);
            u[1] = __expf(lg.y - mx[1]);
            u[2] = __expf(lg.z - mx[2]);
            u[3] = __expf(lg.w - mx[3]);
        }
        int t = tgt[e];
        float m0 = Ptgtm[(size_t)t * 128 + d0];
        float m1 = Ptgtm[(size_t)t * 128 + d1];
#pragma unroll
        for (int k = 0; k < 32; k++) {
            float ek = __shfl(efv, k);
            m0 += ek * W[k][d0];
            m1 += ek * W[k][d1];
        }
        acc0 += u[h0] * m0;
        acc1 += u[h1] * m1;
        den0 += u[h0];
        den1 += u[h1];
    }
    float o0 = (dg > 0) ? acc0 / den0 : 0.f;
    float o1 = (dg > 0) ? acc1 / den1 : 0.f;
    out[(size_t)n * 128 + d0] = o0;
    out[(size_t)n * 128 + d1] = o1;
}

extern "C" void kernel_launch(void* const* d_in, const int* in_sizes, int n_in,
                              void* d_out, int out_size, void* d_ws, size_t ws_size,
                              hipStream_t stream) {
    const float* nf = (const float*)d_in[0];
    const float* ef = (const float*)d_in[1];
    const int* eidx = (const int*)d_in[2];
    const void* mask = d_in[3];
    const float* Wa = (const float*)d_in[4];
    const float* Wm = (const float*)d_in[5];
    const float* aw = (const float*)d_in[6];
    const int* src = eidx;
    const int* tgt = eidx + N_EDGES;
    float* out = (float*)d_out;

    char* ws = (char*)d_ws;
    size_t off = 0;
    auto alloc = [&](size_t bytes) -> void* {
        void* p = ws + off;
        off += (bytes + 255) & ~(size_t)255;
        return p;
    };
    int* mode       = (int*)alloc(256);
    float* Psrc     = (float*)alloc((size_t)N_NODES * 128 * 4);
    float* Ptgta    = (float*)alloc((size_t)N_NODES * 128 * 4);
    float* Ptgtm    = (float*)alloc((size_t)N_NODES * 128 * 4);
    float* logits   = (float*)alloc((size_t)N_EDGES * 4 * 4);
    unsigned* nmax  = (unsigned*)alloc((size_t)N_NODES * 4 * 4);
    int* deg        = (int*)alloc((size_t)N_NODES * 4);
    int* cursor     = (int*)alloc((size_t)N_NODES * 4);
    int* basep      = (int*)alloc((size_t)N_NODES * 4);
    int* csum       = (int*)alloc((size_t)NCH * 4);
    int* order      = (int*)alloc((size_t)N_EDGES * 4);

    hipMemsetAsync(nmax, 0, (size_t)N_NODES * 4 * 4, stream);   // enc(-NaN) = 0 < enc(-inf)
    hipMemsetAsync(deg, 0, (size_t)N_NODES * 4, stream);
    hipMemsetAsync(cursor, 0, (size_t)N_NODES * 4, stream);

    k_detect<<<1, 256, 0, stream>>>((const unsigned char*)mask, mode);
    k_nodegemm<<<dim3((N_NODES + 63) / 64, 3), 256, 0, stream>>>(nf, Wa, Wm, Psrc, Ptgta, Ptgtm);
    k_deg<<<(N_EDGES + 255) / 256, 256, 0, stream>>>(src, deg);
    k_scan_partial<<<NCH, 256, 0, stream>>>(deg, csum);
    k_scan_chunks<<<1, 64, 0, stream>>>(csum);
    k_scan_apply<<<NCH, 1024, 0, stream>>>(deg, csum, basep);
    k_scatter<<<(N_EDGES + 255) / 256, 256, 0, stream>>>(src, basep, cursor, order);
    k_edge<<<N_EDGES / 8, 128, 0, stream>>>(ef, src, tgt, mask, mode, Wa, aw,
                                            Psrc, Ptgta, logits, nmax);
    k_node<<<(N_NODES + 3) / 4, 256, 0, stream>>>(ef, tgt, Wm, Ptgtm, logits, nmax,
                                                  deg, basep, order, out);
}

// Round 2
// 1127.106 us; speedup vs baseline: 1.3678x; 1.3678x over previous
//
#include <hip/hip_runtime.h>
#include <hip/hip_bf16.h>
#include <math.h>

#define N_NODES 50000
#define N_EDGES 800000
#define D_NODE 64
#define D_EDGE 32
#define OUT_DIM 32
#define NUM_HEADS 4
#define HD 128            // NUM_HEADS*OUT_DIM
#define NCH 49            // ceil(N_NODES/1024)

// ---- monotone float<->uint encoding for atomicMax on floats ----
__device__ __forceinline__ unsigned encf(float x) {
    unsigned b = __float_as_uint(x);
    return (b & 0x80000000u) ? ~b : (b | 0x80000000u);
}
__device__ __forceinline__ float decf(unsigned u) {
    unsigned b = (u & 0x80000000u) ? (u & 0x7FFFFFFFu) : ~u;
    return __uint_as_float(b);
}
#define ENC_NEGINF 0x007FFFFFu   // encf(-inf)

// ---- K0: detect attn_mask storage dtype (u8 / f32 / i32) ----
__global__ void k_detect(const unsigned char* __restrict__ mask, int* __restrict__ mode) {
    __shared__ int cnt;
    if (threadIdx.x == 0) cnt = 0;
    __syncthreads();
    int c = 0;
    for (int i = threadIdx.x; i < 4096; i += 256) c += (mask[i] != 0);
    atomicAdd(&cnt, c);
    __syncthreads();
    if (threadIdx.x == 0) {
        int md;
        if (cnt > (4096 * 70) / 100)      md = 0;  // uint8 bool
        else if (cnt > (4096 * 35) / 100) md = 1;  // float32
        else                              md = 2;  // int32
        *mode = md;
    }
}

// ---- K1: node precompute GEMM: P = nf @ Wblk, three [64x128] weight blocks ----
__global__ __launch_bounds__(256) void k_nodegemm(
    const float* __restrict__ nf, const float* __restrict__ Wa, const float* __restrict__ Wm,
    float* __restrict__ Psrc, float* __restrict__ Ptgta, float* __restrict__ Ptgtm) {
    __shared__ float At[64][72];
    __shared__ float Bt[64][128];
    const int mb = blockIdx.y;
    const float* Wsrc = (mb == 0) ? Wa : (mb == 1 ? (Wa + 96 * 128) : (Wm + 32 * 128));
    float* P = (mb == 0) ? Psrc : (mb == 1 ? Ptgta : Ptgtm);
    const int n0 = blockIdx.x * 64;
    const int tid = threadIdx.x;

    for (int i = tid; i < 1024; i += 256) {
        int r = i >> 4;
        int kc = (i & 15) << 2;
        float4 v = make_float4(0.f, 0.f, 0.f, 0.f);
        if (n0 + r < N_NODES) v = *(const float4*)(nf + (size_t)(n0 + r) * 64 + kc);
        At[kc + 0][r] = v.x; At[kc + 1][r] = v.y; At[kc + 2][r] = v.z; At[kc + 3][r] = v.w;
    }
    for (int i = tid; i < 2048; i += 256) {
        int k = i >> 5;
        int c = (i & 31) << 2;
        *(float4*)(&Bt[k][c]) = *(const float4*)(Wsrc + (size_t)k * 128 + c);
    }
    __syncthreads();

    const int ty = tid >> 5;
    const int tx = tid & 31;
    float acc[8][4];
#pragma unroll
    for (int r = 0; r < 8; r++)
#pragma unroll
        for (int c = 0; c < 4; c++) acc[r][c] = 0.f;

    for (int k = 0; k < 64; k++) {
        float4 b = *(const float4*)(&Bt[k][tx * 4]);
        float4 a0 = *(const float4*)(&At[k][ty * 8]);
        float4 a1 = *(const float4*)(&At[k][ty * 8 + 4]);
        float a[8] = {a0.x, a0.y, a0.z, a0.w, a1.x, a1.y, a1.z, a1.w};
#pragma unroll
        for (int r = 0; r < 8; r++) {
            acc[r][0] += a[r] * b.x; acc[r][1] += a[r] * b.y;
            acc[r][2] += a[r] * b.z; acc[r][3] += a[r] * b.w;
        }
    }
    for (int r = 0; r < 8; r++) {
        int n = n0 + ty * 8 + r;
        if (n < N_NODES)
            *(float4*)(P + (size_t)n * 128 + tx * 4) =
                make_float4(acc[r][0], acc[r][1], acc[r][2], acc[r][3]);
    }
}

// ---- K2: degree count ----
__global__ void k_deg(const int* __restrict__ src, int* __restrict__ deg) {
    int i = blockIdx.x * blockDim.x + threadIdx.x;
    if (i < N_EDGES) atomicAdd(&deg[src[i]], 1);
}

// ---- K3a: per-1024-chunk sums ----
__global__ void k_scan_partial(const int* __restrict__ deg, int* __restrict__ csum) {
    __shared__ int sd[256];
    int b = blockIdx.x, tid = threadIdx.x;
    int s = 0, st = b * 1024;
    for (int i = tid; i < 1024; i += 256) {
        int idx = st + i;
        if (idx < N_NODES) s += deg[idx];
    }
    sd[tid] = s; __syncthreads();
    for (int off = 128; off > 0; off >>= 1) {
        if (tid < off) sd[tid] += sd[tid + off];
        __syncthreads();
    }
    if (tid == 0) csum[b] = sd[0];
}

// ---- K3b: exclusive scan of chunk sums ----
__global__ void k_scan_chunks(int* __restrict__ csum) {
    if (threadIdx.x == 0 && blockIdx.x == 0) {
        int acc = 0;
        for (int i = 0; i < NCH; i++) { int v = csum[i]; csum[i] = acc; acc += v; }
    }
}

// ---- K3c: in-chunk scan -> base offsets ----
__global__ __launch_bounds__(1024) void k_scan_apply(
    const int* __restrict__ deg, const int* __restrict__ csum, int* __restrict__ basep) {
    __shared__ int sd[1024];
    int b = blockIdx.x, tid = threadIdx.x;
    int idx = b * 1024 + tid;
    int v = (idx < N_NODES) ? deg[idx] : 0;
    sd[tid] = v; __syncthreads();
    for (int off = 1; off < 1024; off <<= 1) {
        int add = (tid >= off) ? sd[tid - off] : 0;
        __syncthreads();
        sd[tid] += add;
        __syncthreads();
    }
    if (idx < N_NODES) basep[idx] = csum[b] + sd[tid] - v;
}

// ---- K4: scatter edge ids into per-node buckets ----
__global__ void k_scatter(const int* __restrict__ src, const int* __restrict__ basep,
                          int* __restrict__ cursor, int* __restrict__ order) {
    int i = blockIdx.x * blockDim.x + threadIdx.x;
    if (i < N_EDGES) {
        int s = src[i];
        int p = basep[s] + atomicAdd(&cursor[s], 1);
        order[p] = i;
    }
}

// ---- K5: per-edge logits + per-(node,head) max. One wave per 16 edges, no barriers ----
// grid = E/(4*16) = 12500 blocks, 256 threads (4 waves)
#define EPW 16
__global__ void k_edge(
    const float* __restrict__ ef, const int* __restrict__ src, const int* __restrict__ tgt,
    const void* __restrict__ mask, const int* __restrict__ modep,
    const float* __restrict__ Wa, const float* __restrict__ aw,
    const float* __restrict__ Psrc, const float* __restrict__ Ptgta,
    float* __restrict__ logits, unsigned* __restrict__ nmax) {
    const int wv = threadIdx.x >> 6;
    const int lane = threadIdx.x & 63;
    const int d0 = lane, d1 = lane + 64;

    // W_a edge-block columns d0,d1 held in VGPRs (coalesced loads, L2-hot)
    float W0[32], W1[32];
#pragma unroll
    for (int k = 0; k < 32; k++) {
        W0[k] = Wa[(size_t)(64 + k) * 128 + d0];
        W1[k] = Wa[(size_t)(64 + k) * 128 + d1];
    }
    const float awv = aw[lane & 31];
    const int mode = *modep;
    const int base = (blockIdx.x * 4 + wv) * EPW;   // exact fit: 12500*4*16 = 800000

    int s = src[base], t = tgt[base];
    float efv = ef[(size_t)base * 32 + (lane & 31)];

    for (int i = 0; i < EPW; i++) {
        const int e = base + i;
        const int sc = s, tc = t;
        const float efc = efv;
        if (i < EPW - 1) {              // prefetch next edge's chain
            s = src[e + 1]; t = tgt[e + 1];
            efv = ef[(size_t)(e + 1) * 32 + (lane & 31)];
        }
        float a0 = Psrc[(size_t)sc * 128 + d0] + Ptgta[(size_t)tc * 128 + d0];
        float a1 = Psrc[(size_t)sc * 128 + d1] + Ptgta[(size_t)tc * 128 + d1];
#pragma unroll
        for (int k = 0; k < 32; k++) {
            float ek = __shfl(efc, k);
            a0 += ek * W0[k];
            a1 += ek * W1[k];
        }
        float lr0 = (a0 >= 0.f) ? a0 : 0.2f * a0;
        float lr1 = (a1 >= 0.f) ? a1 : 0.2f * a1;
        float v0 = lr0 * awv, v1 = lr1 * awv;
#pragma unroll
        for (int off = 16; off > 0; off >>= 1) {
            v0 += __shfl_xor(v0, off);
            v1 += __shfl_xor(v1, off);
        }
        bool mk;
        if (mode == 0)      mk = ((const unsigned char*)mask)[e] != 0;
        else if (mode == 1) mk = ((const float*)mask)[e] != 0.f;
        else                mk = ((const int*)mask)[e] != 0;
        if ((lane & 31) == 0) {
            const int h = lane >> 5;               // 0 or 1
            float lg0 = mk ? v0 : -INFINITY;       // heads h
            float lg1 = mk ? v1 : -INFINITY;       // heads h+2
            logits[(size_t)e * 4 + h] = lg0;
            logits[(size_t)e * 4 + 2 + h] = lg1;
            atomicMax(nmax + (size_t)sc * 4 + h, encf(lg0));
            atomicMax(nmax + (size_t)sc * 4 + 2 + h, encf(lg1));
        }
    }
}

// ---- K6: node-centric softmax + aggregation. Light per-edge body, per-node GEMM tail ----
// Uses  sum_e u*(ef@Wm) == (sum_e u*ef)@Wm  to hoist the 32x128 GEMM out of the edge loop.
// block 256 = 4 waves (1 node each), grid 12500 (exact)
__global__ __launch_bounds__(256) void k_node(
    const float* __restrict__ ef, const int* __restrict__ tgt,
    const float* __restrict__ Wm, const float* __restrict__ Ptgtm,
    const float* __restrict__ logits, const unsigned* __restrict__ nmax,
    const int* __restrict__ deg, const int* __restrict__ basep,
    const int* __restrict__ order, float* __restrict__ out) {
    __shared__ float Ws[32][128];   // W_m edge block
    const int tid = threadIdx.x;
    for (int i = tid; i < 1024; i += 256) {
        int k = i >> 5;
        int c = (i & 31) << 2;
        *(float4*)(&Ws[k][c]) = *(const float4*)(Wm + (size_t)k * 128 + c);
    }
    __syncthreads();

    const int wv = tid >> 6;
    const int lane = tid & 63;
    const int n = blockIdx.x * 4 + wv;          // exact: 12500*4 = 50000

    const int dg = deg[n], bs = basep[n];
    const int d0 = lane, d1 = lane + 64;
    const int h0 = lane >> 5;                   // head of d0 (0/1)
    const int h1 = h0 + 2;                      // head of d1 (2/3)
    const bool dead = (nmax[(size_t)n * 4] <= ENC_NEGINF);
    const float mxa = decf(nmax[(size_t)n * 4 + h0]);
    const float mxb = decf(nmax[(size_t)n * 4 + h1]);

    float acc0 = 0.f, acc1 = 0.f;               // sum u * Ptgtm
    float w0a = 0.f, w1a = 0.f;                 // sum u * ef   (lane holds (h0,k),(h1,k), k=lane&31)
    float den0 = 0.f, den1 = 0.f;

    int e = 0, t = 0;
    if (dg > 0) { e = order[bs]; t = tgt[e]; }
    for (int i = 0; i < dg; i++) {
        const int ec = e, tc = t;
        if (i + 1 < dg) { e = order[bs + i + 1]; t = tgt[e]; }   // prefetch chain
        float lgA = logits[(size_t)ec * 4 + h0];
        float lgB = logits[(size_t)ec * 4 + h1];
        float u0 = dead ? 1.f : __expf(lgA - mxa);
        float u1 = dead ? 1.f : __expf(lgB - mxb);
        float efv = ef[(size_t)ec * 32 + (lane & 31)];
        float m0 = Ptgtm[(size_t)tc * 128 + d0];
        float m1 = Ptgtm[(size_t)tc * 128 + d1];
        acc0 += u0 * m0;
        acc1 += u1 * m1;
        w0a += u0 * efv;
        w1a += u1 * efv;
        den0 += u0;
        den1 += u1;
    }

    // per-node tail: (sum u*ef) @ Wm_edge for dims d0,d1
    float t0 = 0.f, t1 = 0.f;
#pragma unroll
    for (int k = 0; k < 32; k++) {
        int sl = (lane & 32) + k;               // lane holding wef[h][k] for this half
        float wa = __shfl(w0a, sl);
        float wb = __shfl(w1a, sl);
        t0 += wa * Ws[k][d0];
        t1 += wb * Ws[k][d1];
    }
    float o0 = (dg > 0) ? (acc0 + t0) / den0 : 0.f;
    float o1 = (dg > 0) ? (acc1 + t1) / den1 : 0.f;
    out[(size_t)n * 128 + d0] = o0;
    out[(size_t)n * 128 + d1] = o1;
}

extern "C" void kernel_launch(void* const* d_in, const int* in_sizes, int n_in,
                              void* d_out, int out_size, void* d_ws, size_t ws_size,
                              hipStream_t stream) {
    const float* nf = (const float*)d_in[0];
    const float* ef = (const float*)d_in[1];
    const int* eidx = (const int*)d_in[2];
    const void* mask = d_in[3];
    const float* Wa = (const float*)d_in[4];
    const float* Wm = (const float*)d_in[5];
    const float* aw = (const float*)d_in[6];
    const int* src = eidx;
    const int* tgt = eidx + N_EDGES;
    float* out = (float*)d_out;

    char* ws = (char*)d_ws;
    size_t off = 0;
    auto alloc = [&](size_t bytes) -> void* {
        void* p = ws + off;
        off += (bytes + 255) & ~(size_t)255;
        return p;
    };
    int* mode       = (int*)alloc(256);
    float* Psrc     = (float*)alloc((size_t)N_NODES * 128 * 4);
    float* Ptgta    = (float*)alloc((size_t)N_NODES * 128 * 4);
    float* Ptgtm    = (float*)alloc((size_t)N_NODES * 128 * 4);
    float* logits   = (float*)alloc((size_t)N_EDGES * 4 * 4);
    unsigned* nmax  = (unsigned*)alloc((size_t)N_NODES * 4 * 4);
    int* deg        = (int*)alloc((size_t)N_NODES * 4);
    int* cursor     = (int*)alloc((size_t)N_NODES * 4);
    int* basep      = (int*)alloc((size_t)N_NODES * 4);
    int* csum       = (int*)alloc((size_t)NCH * 4);
    int* order      = (int*)alloc((size_t)N_EDGES * 4);

    hipMemsetAsync(nmax, 0, (size_t)N_NODES * 4 * 4, stream);
    hipMemsetAsync(deg, 0, (size_t)N_NODES * 4, stream);
    hipMemsetAsync(cursor, 0, (size_t)N_NODES * 4, stream);

    k_detect<<<1, 256, 0, stream>>>((const unsigned char*)mask, mode);
    k_nodegemm<<<dim3((N_NODES + 63) / 64, 3), 256, 0, stream>>>(nf, Wa, Wm, Psrc, Ptgta, Ptgtm);
    k_deg<<<(N_EDGES + 255) / 256, 256, 0, stream>>>(src, deg);
    k_scan_partial<<<NCH, 256, 0, stream>>>(deg, csum);
    k_scan_chunks<<<1, 64, 0, stream>>>(csum);
    k_scan_apply<<<NCH, 1024, 0, stream>>>(deg, csum, basep);
    k_scatter<<<(N_EDGES + 255) / 256, 256, 0, stream>>>(src, basep, cursor, order);
    k_edge<<<N_EDGES / (4 * EPW), 256, 0, stream>>>(ef, src, tgt, mask, mode, Wa, aw,
                                                    Psrc, Ptgta, logits, nmax);
    k_node<<<N_NODES / 4, 256, 0, stream>>>(ef, tgt, Wm, Ptgtm, logits, nmax,
                                            deg, basep, order, out);
}

// Round 5
// 768.110 us; speedup vs baseline: 2.0071x; 1.4674x over previous
//
#include <hip/hip_runtime.h>
#include <hip/hip_bf16.h>
#include <math.h>

#define N_NODES 50000
#define N_EDGES 800000
#define D_NODE 64
#define D_EDGE 32
#define OUT_DIM 32
#define NUM_HEADS 4
#define NCH 49            // ceil(N_NODES/1024)

// ---- bf16 helpers (manual RNE pack, shift unpack) ----
__device__ __forceinline__ unsigned bf16rne(float x) {
    unsigned u = __float_as_uint(x);
    unsigned r = ((u >> 16) & 1u) + 0x7fffu;
    return (u + r) >> 16;
}
__device__ __forceinline__ float2 unpack_bf2(unsigned p) {
    return make_float2(__uint_as_float(p << 16), __uint_as_float(p & 0xffff0000u));
}

// ---- K0: detect attn_mask storage dtype (u8 / f32 / i32) ----
__global__ void k_detect(const unsigned char* __restrict__ mask, int* __restrict__ mode) {
    __shared__ int cnt;
    if (threadIdx.x == 0) cnt = 0;
    __syncthreads();
    int c = 0;
    for (int i = threadIdx.x; i < 4096; i += 256) c += (mask[i] != 0);
    atomicAdd(&cnt, c);
    __syncthreads();
    if (threadIdx.x == 0) {
        int md;
        if (cnt > (4096 * 70) / 100)      md = 0;  // uint8 bool
        else if (cnt > (4096 * 35) / 100) md = 1;  // float32
        else                              md = 2;  // int32
        *mode = md;
    }
}

__device__ __forceinline__ bool loadmask(const void* m, int mode, int e) {
    if (mode == 0) return ((const unsigned char*)m)[e] != 0;
    if (mode == 1) return ((const float*)m)[e] != 0.f;
    return ((const int*)m)[e] != 0;
}

// ---- K1: node precompute GEMM ----
// mb=0: Psrc (fp32) = nf @ Wa[0:64]
// mb=1: PT[:, 0:128]  (bf16) = nf @ Wa[96:160]   (tgt block of W_a)
// mb=2: PT[:, 128:256](bf16) = nf @ Wm[32:96]    (tgt block of W_m)
__global__ __launch_bounds__(256) void k_nodegemm(
    const float* __restrict__ nf, const float* __restrict__ Wa, const float* __restrict__ Wm,
    float* __restrict__ Psrc, unsigned* __restrict__ PT) {
    __shared__ float At[64][72];
    __shared__ float Bt[64][128];
    const int mb = blockIdx.y;
    const float* Wsrc = (mb == 0) ? Wa : (mb == 1 ? (Wa + 96 * 128) : (Wm + 32 * 128));
    const int n0 = blockIdx.x * 64;
    const int tid = threadIdx.x;

    for (int i = tid; i < 1024; i += 256) {
        int r = i >> 4;
        int kc = (i & 15) << 2;
        float4 v = make_float4(0.f, 0.f, 0.f, 0.f);
        if (n0 + r < N_NODES) v = *(const float4*)(nf + (size_t)(n0 + r) * 64 + kc);
        At[kc + 0][r] = v.x; At[kc + 1][r] = v.y; At[kc + 2][r] = v.z; At[kc + 3][r] = v.w;
    }
    for (int i = tid; i < 2048; i += 256) {
        int k = i >> 5;
        int c = (i & 31) << 2;
        *(float4*)(&Bt[k][c]) = *(const float4*)(Wsrc + (size_t)k * 128 + c);
    }
    __syncthreads();

    const int ty = tid >> 5;
    const int tx = tid & 31;
    float acc[8][4];
#pragma unroll
    for (int r = 0; r < 8; r++)
#pragma unroll
        for (int c = 0; c < 4; c++) acc[r][c] = 0.f;

    for (int k = 0; k < 64; k++) {
        float4 b = *(const float4*)(&Bt[k][tx * 4]);
        float4 a0 = *(const float4*)(&At[k][ty * 8]);
        float4 a1 = *(const float4*)(&At[k][ty * 8 + 4]);
        float a[8] = {a0.x, a0.y, a0.z, a0.w, a1.x, a1.y, a1.z, a1.w};
#pragma unroll
        for (int r = 0; r < 8; r++) {
            acc[r][0] += a[r] * b.x; acc[r][1] += a[r] * b.y;
            acc[r][2] += a[r] * b.z; acc[r][3] += a[r] * b.w;
        }
    }
    for (int r = 0; r < 8; r++) {
        int n = n0 + ty * 8 + r;
        if (n >= N_NODES) continue;
        if (mb == 0) {
            *(float4*)(Psrc + (size_t)n * 128 + tx * 4) =
                make_float4(acc[r][0], acc[r][1], acc[r][2], acc[r][3]);
        } else {
            unsigned p0 = bf16rne(acc[r][0]) | (bf16rne(acc[r][1]) << 16);
            unsigned p1 = bf16rne(acc[r][2]) | (bf16rne(acc[r][3]) << 16);
            unsigned base = (mb == 1) ? 0u : 64u;
            *(uint2*)(PT + (size_t)n * 128 + base + tx * 2) = make_uint2(p0, p1);
        }
    }
}

// ---- K2: degree count ----
__global__ void k_deg(const int* __restrict__ src, int* __restrict__ deg) {
    int i = blockIdx.x * blockDim.x + threadIdx.x;
    if (i < N_EDGES) atomicAdd(&deg[src[i]], 1);
}

// ---- K3a: per-1024-chunk sums ----
__global__ void k_scan_partial(const int* __restrict__ deg, int* __restrict__ csum) {
    __shared__ int sd[256];
    int b = blockIdx.x, tid = threadIdx.x;
    int s = 0, st = b * 1024;
    for (int i = tid; i < 1024; i += 256) {
        int idx = st + i;
        if (idx < N_NODES) s += deg[idx];
    }
    sd[tid] = s; __syncthreads();
    for (int off = 128; off > 0; off >>= 1) {
        if (tid < off) sd[tid] += sd[tid + off];
        __syncthreads();
    }
    if (tid == 0) csum[b] = sd[0];
}

// ---- K3b: exclusive scan of chunk sums ----
__global__ void k_scan_chunks(int* __restrict__ csum) {
    if (threadIdx.x == 0 && blockIdx.x == 0) {
        int acc = 0;
        for (int i = 0; i < NCH; i++) { int v = csum[i]; csum[i] = acc; acc += v; }
    }
}

// ---- K3c: in-chunk scan -> base offsets ----
__global__ __launch_bounds__(1024) void k_scan_apply(
    const int* __restrict__ deg, const int* __restrict__ csum, int* __restrict__ basep) {
    __shared__ int sd[1024];
    int b = blockIdx.x, tid = threadIdx.x;
    int idx = b * 1024 + tid;
    int v = (idx < N_NODES) ? deg[idx] : 0;
    sd[tid] = v; __syncthreads();
    for (int off = 1; off < 1024; off <<= 1) {
        int add = (tid >= off) ? sd[tid - off] : 0;
        __syncthreads();
        sd[tid] += add;
        __syncthreads();
    }
    if (idx < N_NODES) basep[idx] = csum[b] + sd[tid] - v;
}

// ---- K4: scatter edge ids into per-node buckets ----
__global__ void k_scatter(const int* __restrict__ src, const int* __restrict__ basep,
                          int* __restrict__ cursor, int* __restrict__ order) {
    int i = blockIdx.x * blockDim.x + threadIdx.x;
    if (i < N_EDGES) {
        int s = src[i];
        int p = basep[s] + atomicAdd(&cursor[s], 1);
        order[p] = i;
    }
}

// ---- K5: fully fused per-node GATv2 ----
// Wave per node over src-sorted edges. Lane l: head h=l>>4, dims (2l, 2l+1).
// No max pass: u = exp(min(logit,60)); masked -> 0; dead node <=> den==0 -> uniform fallback.
// Per-edge message GEMM factored out: sum_e u*(ef@Wm) == (sum_e u*ef)@Wm (per-node tail).
__global__ __launch_bounds__(256) void k_fused(
    const float* __restrict__ ef, const int* __restrict__ tgt,
    const void* __restrict__ mask, const int* __restrict__ modep,
    const float* __restrict__ Wa, const float* __restrict__ Wm, const float* __restrict__ aw,
    const float* __restrict__ Psrc, const unsigned* __restrict__ PT,
    const int* __restrict__ deg, const int* __restrict__ basep,
    const int* __restrict__ order, float* __restrict__ out) {
    const int lane = threadIdx.x & 63;
    const int wv = threadIdx.x >> 6;
    const int n = blockIdx.x * 4 + wv;          // exact: 12500*4 = 50000
    const int l15 = lane & 15;
    const int base16 = lane & 48;
    const int d0 = lane * 2;                    // global dims d0, d0+1 (same head)

    // W_a edge-block columns (d0,d0+1) in VGPRs: W[j] = (Wa[64+j][d0], Wa[64+j][d0+1])
    float2 W[32];
#pragma unroll
    for (int j = 0; j < 32; j++)
        W[j] = *(const float2*)(Wa + (size_t)(64 + j) * 128 + d0);

    const float2 awv = *(const float2*)(aw + 2 * l15);
    const int mode = *modep;
    const int dg = deg[n], bs = basep[n];
    const float2 ps = *(const float2*)(Psrc + (size_t)n * 128 + d0);

    float acc0 = 0.f, acc1 = 0.f;     // sum u * Ptgtm  (this lane's 2 dims)
    float w0 = 0.f, w1 = 0.f;         // sum u * ef     (this head, k = 2*l15, 2*l15+1)
    float den = 0.f;
    float accU0 = 0.f, accU1 = 0.f;   // uniform fallback (dead nodes)
    float wU0 = 0.f, wU1 = 0.f;

    // 3-stage pipeline: order 3 ahead, tgt 2 ahead, row data 1 ahead
    const int last = N_EDGES - 1;
    int e1 = order[min(bs + 0, last)];
    int e2 = order[min(bs + 1, last)];
    int e3 = order[min(bs + 2, last)];
    int t1 = tgt[e1];
    int t2 = tgt[e2];
    unsigned pa = PT[(size_t)t1 * 128 + lane];
    unsigned pm = PT[(size_t)t1 * 128 + 64 + lane];
    float2 efc = *(const float2*)(ef + (size_t)e1 * 32 + 2 * l15);
    bool mkc = loadmask(mask, mode, e1);

    for (int i = 0; i < dg; i++) {
        // issue stage-3: order for i+3
        int e4 = order[min(bs + i + 3, last)];
        // issue stage-2: tgt for i+2
        int t3 = tgt[e3];
        // issue stage-1: row data for i+1
        unsigned paN = PT[(size_t)t2 * 128 + lane];
        unsigned pmN = PT[(size_t)t2 * 128 + 64 + lane];
        float2 efN = *(const float2*)(ef + (size_t)e2 * 32 + 2 * l15);
        bool mkN = loadmask(mask, mode, e2);

        // compute on edge i
        float2 paf = unpack_bf2(pa);
        float a0 = ps.x + paf.x;
        float a1 = ps.y + paf.y;
#pragma unroll
        for (int j = 0; j < 32; j += 2) {
            int sl = base16 + (j >> 1);
            float ex = __shfl(efc.x, sl);
            float ey = __shfl(efc.y, sl);
            a0 += ex * W[j].x + ey * W[j + 1].x;
            a1 += ex * W[j].y + ey * W[j + 1].y;
        }
        float lr0 = (a0 >= 0.f) ? a0 : 0.2f * a0;
        float lr1 = (a1 >= 0.f) ? a1 : 0.2f * a1;
        float v = lr0 * awv.x + lr1 * awv.y;
        v += __shfl_xor(v, 8);
        v += __shfl_xor(v, 4);
        v += __shfl_xor(v, 2);
        v += __shfl_xor(v, 1);
        float u = mkc ? __expf(fminf(v, 60.f)) : 0.f;

        float2 pmf = unpack_bf2(pm);
        acc0 += u * pmf.x; acc1 += u * pmf.y;
        w0 += u * efc.x;   w1 += u * efc.y;
        den += u;
        accU0 += pmf.x;    accU1 += pmf.y;
        wU0 += efc.x;      wU1 += efc.y;

        // rotate pipeline
        pa = paN; pm = pmN; efc = efN; mkc = mkN;
        e2 = e3; e3 = e4; t2 = t3;
    }

    // dead-node (all edges masked) -> uniform weights over all edges
    bool dead = (dg > 0) && (den == 0.f);
    float sw0 = dead ? wU0 : w0, sw1 = dead ? wU1 : w1;
    float sa0 = dead ? accU0 : acc0, sa1 = dead ? accU1 : acc1;
    float sden = dead ? (float)dg : den;

    // per-node tail: (sum u*ef) @ Wm_edge for dims d0, d0+1
    float t0 = 0.f, tt1 = 0.f;
#pragma unroll
    for (int k = 0; k < 32; k += 2) {
        int sl = base16 + (k >> 1);
        float wa = __shfl(sw0, sl);
        float wb = __shfl(sw1, sl);
        float2 m0 = *(const float2*)(Wm + (size_t)k * 128 + d0);
        float2 m1 = *(const float2*)(Wm + (size_t)(k + 1) * 128 + d0);
        t0  += wa * m0.x + wb * m1.x;
        tt1 += wa * m0.y + wb * m1.y;
    }
    float o0 = (dg > 0) ? (sa0 + t0) / sden : 0.f;
    float o1 = (dg > 0) ? (sa1 + tt1) / sden : 0.f;
    *(float2*)(out + (size_t)n * 128 + d0) = make_float2(o0, o1);
}

extern "C" void kernel_launch(void* const* d_in, const int* in_sizes, int n_in,
                              void* d_out, int out_size, void* d_ws, size_t ws_size,
                              hipStream_t stream) {
    const float* nf = (const float*)d_in[0];
    const float* ef = (const float*)d_in[1];
    const int* eidx = (const int*)d_in[2];
    const void* mask = d_in[3];
    const float* Wa = (const float*)d_in[4];
    const float* Wm = (const float*)d_in[5];
    const float* aw = (const float*)d_in[6];
    const int* src = eidx;
    const int* tgt = eidx + N_EDGES;
    float* out = (float*)d_out;

    char* ws = (char*)d_ws;
    size_t off = 0;
    auto alloc = [&](size_t bytes) -> void* {
        void* p = ws + off;
        off += (bytes + 255) & ~(size_t)255;
        return p;
    };
    int* mode       = (int*)alloc(256);
    float* Psrc     = (float*)alloc((size_t)N_NODES * 128 * 4);
    unsigned* PT    = (unsigned*)alloc((size_t)N_NODES * 128 * 4);  // [N][256] bf16
    int* deg        = (int*)alloc((size_t)N_NODES * 4);
    int* cursor     = (int*)alloc((size_t)N_NODES * 4);
    int* basep      = (int*)alloc((size_t)N_NODES * 4);
    int* csum       = (int*)alloc((size_t)NCH * 4);
    int* order      = (int*)alloc((size_t)N_EDGES * 4);

    hipMemsetAsync(deg, 0, (size_t)N_NODES * 4, stream);
    hipMemsetAsync(cursor, 0, (size_t)N_NODES * 4, stream);

    k_detect<<<1, 256, 0, stream>>>((const unsigned char*)mask, mode);
    k_nodegemm<<<dim3((N_NODES + 63) / 64, 3), 256, 0, stream>>>(nf, Wa, Wm, Psrc, PT);
    k_deg<<<(N_EDGES + 255) / 256, 256, 0, stream>>>(src, deg);
    k_scan_partial<<<NCH, 256, 0, stream>>>(deg, csum);
    k_scan_chunks<<<1, 64, 0, stream>>>(csum);
    k_scan_apply<<<NCH, 1024, 0, stream>>>(deg, csum, basep);
    k_scatter<<<(N_EDGES + 255) / 256, 256, 0, stream>>>(src, basep, cursor, order);
    k_fused<<<N_NODES / 4, 256, 0, stream>>>(ef, tgt, mask, mode, Wa, Wm, aw,
                                             Psrc, PT, deg, basep, order, out);
}